// Round 5
// baseline (1271.808 us; speedup 1.0000x reference)
//
#include <hip/hip_runtime.h>

// ---------------------------------------------------------------------------
// ChemistryAwareDecoder on MI355X (gfx950)
// N=100000 nodes, E=200000 edges, SD=128, CD=768
// R5: R4's barrier-free f16x2 design, but the 24 N-tiles are SPLIT ACROSS
// 4 WAVES per block (R4 gave one wave all 24 -> ~270 live regs -> 83 MB of
// spill stores, MfmaUtil 9.5%). Wave wv owns S{wv}, H{4+3wv..6+3wv},
// C{16+2wv,17+2wv}: phase-B live accs 40 regs, est. total ~140 -> fits
// __launch_bounds__(256,3) (~168 cap) with margin, 12 waves/CU, no spill.
// Each wave gathers the same 32-edge rows (L1-shared, HBM compulsory
// unchanged). No per-K-step sync; 2 __syncthreads total (init + final sum).
// Spill tripwire: WRITE_SIZE must drop 83.6 MB -> ~0.9 MB.
// ---------------------------------------------------------------------------

typedef float    f32x4 __attribute__((ext_vector_type(4)));
typedef _Float16 f16x8 __attribute__((ext_vector_type(8)));

#define E_EDGES 200000
#define KSTEPS  28                    // 896 / 32
#define NOUT    384                   // 64 + 192 + 128 fused outputs
#define PTOT    (KSTEPS * NOUT * 32)  // 344064 weight elements
#define PANEL   (NOUT * 32)           // 12288 halfs per k-step panel

// workspace layout (bytes)
#define WS_WH    0
#define WS_B1    688128
#define WS_W2    (688128 + 1536)
#define WS_CONST (688128 + 3072)

// ---------------------------------------------------------------------------
// Prep: fused block-diagonal weight panels in f16 (RNE), fused bias/layer-2
// vectors, softmax consts, edge-dtype detection.
// Panel: wh[p][n][kk], p = k/32, n = 0..383, kk = k%32.
// Wbig[k][n]: n<64: sw1 (k<128) | n<256: cw1 (k>=128) | n>=256: mw1 (all k)
// ---------------------------------------------------------------------------
__global__ __launch_bounds__(256) void prep_kernel(
    const float* __restrict__ sw1, const float* __restrict__ sb1,
    const float* __restrict__ sw2, const float* __restrict__ sb2,
    const float* __restrict__ cw1, const float* __restrict__ cb1,
    const float* __restrict__ cw2, const float* __restrict__ cb2,
    const float* __restrict__ mw1, const float* __restrict__ mb1,
    const float* __restrict__ mw2, const float* __restrict__ mb2,
    const float* __restrict__ pw,  const int* __restrict__ edge_i32,
    _Float16* __restrict__ wh,
    float* __restrict__ b1cat, float* __restrict__ w2cat,
    float* __restrict__ consts)
{
  const int idx = blockIdx.x * 256 + threadIdx.x;
  if (idx < PTOT) {
    const int p  = idx / PANEL;
    const int r  = idx % PANEL;
    const int n  = r >> 5;
    const int kk = r & 31;
    const int k  = p * 32 + kk;
    float v;
    if (n < 64)       v = (k < 128)  ? sw1[k * 64 + n] : 0.0f;
    else if (n < 256) v = (k >= 128) ? cw1[(size_t)(k - 128) * 192 + (n - 64)] : 0.0f;
    else              v = mw1[(size_t)k * 128 + (n - 256)];
    wh[idx] = (_Float16)v;  // RNE
  } else if (idx < PTOT + NOUT) {
    const int j = idx - PTOT;
    float b, w;
    if (j < 64)       { b = sb1[j];       w = sw2[j]; }
    else if (j < 256) { b = cb1[j - 64];  w = cw2[j - 64]; }
    else              { b = mb1[j - 256]; w = mw2[j - 256]; }
    b1cat[j] = b;
    w2cat[j] = w;
  } else if (idx == PTOT + NOUT) {
    const float p0 = pw[0], p1 = pw[1], p2 = pw[2];
    const float mx = fmaxf(p0, fmaxf(p1, p2));
    const float e0 = __expf(p0 - mx), e1 = __expf(p1 - mx), e2 = __expf(p2 - mx);
    const float inv = 1.0f / (e0 + e1 + e2);
    const float w0 = e0 * inv, w1 = e1 * inv, w2v = e2 * inv;
    consts[0] = w0; consts[1] = w1; consts[2] = w2v;
    consts[3] = w0 * sb2[0] + w1 * cb2[0] + w2v * mb2[0];  // valid-path bias
    consts[4] = sb2[0];                                    // invalid-path bias
    unsigned o = 0;
    for (int i = 0; i < 64; ++i) o |= (unsigned)edge_i32[2 * i + 1];
    consts[5] = (o == 0u) ? 1.0f : 0.0f;  // 1 => int64 edge layout
  }
}

// f16x2 compensated: (ah+al)*bh = a*bh; error ~ 2^-12 |ab| per term
#define FMA2(ACC, AH, AL, B)                                              \
  ACC = __builtin_amdgcn_mfma_f32_16x16x32_f16(AH, B, ACC, 0, 0, 0);      \
  ACC = __builtin_amdgcn_mfma_f32_16x16x32_f16(AL, B, ACC, 0, 0, 0);

// ---------------------------------------------------------------------------
// Main: grid = E/32 = 6250 blocks of 256 threads (4 waves). Block owns edges
// [32b, 32b+32): M-tile0 rows 0-15, tile1 rows 16-31. N-tiles: 0-3
// structural (k<128), 4-15 chemical (k>=128), 16-23 combined (all k).
// Wave wv: S{wv} (phase A), H{4+3wv,5+3wv,6+3wv} (phase B), C{16+2wv,17+2wv}
// (both phases). All 4 waves gather the same A data (L1-shared).
// ---------------------------------------------------------------------------
__global__ __launch_bounds__(256, 3) void decoder_main(
    const float* __restrict__ z, const float* __restrict__ chem,
    const int* __restrict__ edge, const int* __restrict__ mask,
    const _Float16* __restrict__ wh,
    const float* __restrict__ b1cat, const float* __restrict__ w2cat,
    const float* __restrict__ consts, float* __restrict__ out)
{
  __shared__ float scoreW[4][32];
  __shared__ float validL[32];

  const int tid  = threadIdx.x;
  const int lane = tid & 63;
  const int wv   = tid >> 6;
  const int li   = lane & 15;
  const int q    = lane >> 4;
  const int kq   = q * 8;
  const int base = blockIdx.x * 32;   // E = 6250*32 exactly

  // edges for this lane's rows: r0 = li (tile0), r1 = 16+li (tile1).
  const int e0 = base + li;
  const int e1 = base + 16 + li;
  int s0, d0, s1, d1;
  if (consts[5] > 0.5f) {
    s0 = edge[4 * e0]; d0 = edge[4 * e0 + 2];
    s1 = edge[4 * e1]; d1 = edge[4 * e1 + 2];
  } else {
    s0 = edge[2 * e0]; d0 = edge[2 * e0 + 1];
    s1 = edge[2 * e1]; d1 = edge[2 * e1 + 1];
  }
  const float v0 = (mask[s0] != 0 && mask[d0] != 0) ? 1.0f : 0.0f;
  const float v1 = (mask[s1] != 0 && mask[d1] != 0) ? 1.0f : 0.0f;

  if (tid < 16) { validL[tid] = v0; validL[16 + tid] = v1; }
  __syncthreads();   // validL visible before final phase (and LDS alloc'd)

  // gather stream pointers (lane's k-chunk baked in)
  const float* zs0 = z + (size_t)s0 * 128 + kq;
  const float* zd0 = z + (size_t)d0 * 128 + kq;
  const float* zs1 = z + (size_t)s1 * 128 + kq;
  const float* zd1 = z + (size_t)d1 * 128 + kq;
  const float* cs0 = chem + (size_t)s0 * 768 + kq;
  const float* cd0 = chem + (size_t)d0 * 768 + kq;
  const float* cs1 = chem + (size_t)s1 * 768 + kq;
  const float* cd1 = chem + (size_t)d1 * 768 + kq;

  // prefetch registers: 8 x f32x4 (2 per stream)
  f32x4 gs0a, gs0b, gd0a, gd0b, gs1a, gs1b, gd1a, gd1b;
#define LD8(P, OFF, A, B)                        \
  A = *(const f32x4*)((P) + (OFF));              \
  B = *(const f32x4*)((P) + (OFF) + 4);

  // products -> A-frag (f16 hi + lo). Lane holds A[row][kq + j], j=0..7:
  // exactly the 16x16x32 A layout (m = lane&15, k = q*8+j).
#define MKFRAG(SA, SB, DA, DB, AH, AL)           \
  {                                              \
    _Pragma("unroll")                            \
    for (int j = 0; j < 4; ++j) {                \
      const float p  = (SA)[j] * (DA)[j];        \
      const _Float16 h = (_Float16)p;            \
      (AH)[j] = h;                               \
      (AL)[j] = (_Float16)(p - (float)h);        \
      const float p2 = (SB)[j] * (DB)[j];        \
      const _Float16 h2 = (_Float16)p2;          \
      (AH)[4 + j] = h2;                          \
      (AL)[4 + j] = (_Float16)(p2 - (float)h2);  \
    }                                            \
  }

  // B fragment: tile ti at step s (proven panel indexing)
#define BFRAG(S, TI) \
  (*(const f16x8*)(wh + (size_t)(S) * PANEL + ((TI) * 16 + li) * 32 + q * 8))

  const float w0c = consts[0], w1c = consts[1], w2c = consts[2];

  float part[2][4];
#pragma unroll
  for (int mt = 0; mt < 2; ++mt)
#pragma unroll
    for (int r = 0; r < 4; ++r) part[mt][r] = 0.0f;

  // retire one tile's acc into part with path weighting.
  // C/D layout: col = ti*16+li, row = q*4+r (+16 for tile1).
  // Called only in uniform control flow (shuffle sources must be live).
#define RETIRE(ACC, TI, MT, WVALID, WINVALID)                              \
  {                                                                        \
    const int col = (TI) * 16 + li;                                        \
    const float b1 = b1cat[col];                                           \
    const float w2 = w2cat[col];                                           \
    _Pragma("unroll")                                                      \
    for (int r = 0; r < 4; ++r) {                                          \
      const float vld = __shfl((MT) ? v1 : v0, q * 4 + r);                 \
      const float a = (WINVALID) + vld * ((WVALID) - (WINVALID));          \
      part[MT][r] += a * fmaxf((ACC)[r] + b1, 0.0f) * w2;                  \
    }                                                                      \
  }

  // this wave's tile indices
  const int tS  = wv;             // structural, phase A
  const int tH0 = 4 + 3 * wv;     // chemical, phase B
  const int tC0 = 16 + 2 * wv;    // combined, both phases

  // ---------------- phase A: s = 0..3 (z gathers; S + C tiles) ----------
  f32x4 accS[2], accC[2][2];
  accS[0] = (f32x4){0.f, 0.f, 0.f, 0.f};
  accS[1] = (f32x4){0.f, 0.f, 0.f, 0.f};
#pragma unroll
  for (int t = 0; t < 2; ++t) {
    accC[t][0] = (f32x4){0.f, 0.f, 0.f, 0.f};
    accC[t][1] = (f32x4){0.f, 0.f, 0.f, 0.f};
  }

  LD8(zs0, 0, gs0a, gs0b) LD8(zd0, 0, gd0a, gd0b)
  LD8(zs1, 0, gs1a, gs1b) LD8(zd1, 0, gd1a, gd1b)

#pragma unroll
  for (int s = 0; s < 4; ++s) {
    f16x8 a0h, a0l, a1h, a1l;
    MKFRAG(gs0a, gs0b, gd0a, gd0b, a0h, a0l)
    MKFRAG(gs1a, gs1b, gd1a, gd1b, a1h, a1l)

    // prefetch next step's gathers (hidden under the MFMA block below)
    if (s < 3) {
      const int off = (s + 1) * 32;
      LD8(zs0, off, gs0a, gs0b) LD8(zd0, off, gd0a, gd0b)
      LD8(zs1, off, gs1a, gs1b) LD8(zd1, off, gd1a, gd1b)
    } else {
      LD8(cs0, 0, gs0a, gs0b) LD8(cd0, 0, gd0a, gd0b)
      LD8(cs1, 0, gs1a, gs1b) LD8(cd1, 0, gd1a, gd1b)
    }

    {
      const f16x8 b = BFRAG(s, tS);
      FMA2(accS[0], a0h, a0l, b)
      FMA2(accS[1], a1h, a1l, b)
    }
#pragma unroll
    for (int t = 0; t < 2; ++t) {
      const f16x8 b = BFRAG(s, tC0 + t);
      FMA2(accC[t][0], a0h, a0l, b)
      FMA2(accC[t][1], a1h, a1l, b)
    }
  }

  // retire structural (k-range done): valid ? w0 : 1
  RETIRE(accS[0], tS, 0, w0c, 1.0f)
  RETIRE(accS[1], tS, 1, w0c, 1.0f)

  // ---------------- phase B: s = 4..27 (chem gathers; H + C tiles) ------
  f32x4 accH[3][2];
#pragma unroll
  for (int t = 0; t < 3; ++t) {
    accH[t][0] = (f32x4){0.f, 0.f, 0.f, 0.f};
    accH[t][1] = (f32x4){0.f, 0.f, 0.f, 0.f};
  }

  for (int s = 4; s < KSTEPS; ++s) {
    f16x8 a0h, a0l, a1h, a1l;
    MKFRAG(gs0a, gs0b, gd0a, gd0b, a0h, a0l)
    MKFRAG(gs1a, gs1b, gd1a, gd1b, a1h, a1l)

    if (s + 1 < KSTEPS) {
      const int off = (s + 1) * 32 - 128;
      LD8(cs0, off, gs0a, gs0b) LD8(cd0, off, gd0a, gd0b)
      LD8(cs1, off, gs1a, gs1b) LD8(cd1, off, gd1a, gd1b)
    }

#pragma unroll
    for (int t = 0; t < 3; ++t) {
      const f16x8 b = BFRAG(s, tH0 + t);
      FMA2(accH[t][0], a0h, a0l, b)
      FMA2(accH[t][1], a1h, a1l, b)
    }
#pragma unroll
    for (int t = 0; t < 2; ++t) {
      const f16x8 b = BFRAG(s, tC0 + t);
      FMA2(accC[t][0], a0h, a0l, b)
      FMA2(accC[t][1], a1h, a1l, b)
    }
  }

  // retire chemical (valid ? w1 : 0) and combined (valid ? w2 : 0)
#pragma unroll
  for (int t = 0; t < 3; ++t) {
    RETIRE(accH[t][0], tH0 + t, 0, w1c, 0.0f)
    RETIRE(accH[t][1], tH0 + t, 1, w1c, 0.0f)
  }
#pragma unroll
  for (int t = 0; t < 2; ++t) {
    RETIRE(accC[t][0], tC0 + t, 0, w2c, 0.0f)
    RETIRE(accC[t][1], tC0 + t, 1, w2c, 0.0f)
  }

  // ---------------- reduce 16 cols per quad (uniform flow) ---------------
#pragma unroll
  for (int mt = 0; mt < 2; ++mt) {
#pragma unroll
    for (int r = 0; r < 4; ++r) {
      float vv = part[mt][r];
      vv += __shfl_xor(vv, 1);
      vv += __shfl_xor(vv, 2);
      vv += __shfl_xor(vv, 4);
      vv += __shfl_xor(vv, 8);
      part[mt][r] = vv;   // full sum now in every lane
    }
  }
  // per-wave partials to LDS (plain stores, no cross-lane in divergent flow)
  if (li == 0) {
#pragma unroll
    for (int mt = 0; mt < 2; ++mt)
#pragma unroll
      for (int r = 0; r < 4; ++r)
        scoreW[wv][mt * 16 + q * 4 + r] = part[mt][r];
  }
  __syncthreads();

  // final cross-wave sum + bias select
  if (tid < 32) {
    const float s4 = scoreW[0][tid] + scoreW[1][tid] + scoreW[2][tid] + scoreW[3][tid];
    const float c3 = consts[3], c4 = consts[4];
    out[base + tid] = s4 + c4 + validL[tid] * (c3 - c4);
  }
}

// ---------------------------------------------------------------------------
extern "C" void kernel_launch(void* const* d_in, const int* in_sizes, int n_in,
                              void* d_out, int out_size, void* d_ws, size_t ws_size,
                              hipStream_t stream)
{
  const float* z    = (const float*)d_in[0];
  const float* chem = (const float*)d_in[1];
  const int*   edge = (const int*)d_in[2];
  const int*   mask = (const int*)d_in[3];
  const float* sw1  = (const float*)d_in[4];
  const float* sb1  = (const float*)d_in[5];
  const float* sw2  = (const float*)d_in[6];
  const float* sb2  = (const float*)d_in[7];
  const float* cw1  = (const float*)d_in[8];
  const float* cb1  = (const float*)d_in[9];
  const float* cw2  = (const float*)d_in[10];
  const float* cb2  = (const float*)d_in[11];
  const float* mw1  = (const float*)d_in[12];
  const float* mb1  = (const float*)d_in[13];
  const float* mw2  = (const float*)d_in[14];
  const float* mb2  = (const float*)d_in[15];
  const float* pw   = (const float*)d_in[16];

  char* ws = (char*)d_ws;
  _Float16* wh  = (_Float16*)(ws + WS_WH);
  float* b1cat  = (float*)(ws + WS_B1);
  float* w2cat  = (float*)(ws + WS_W2);
  float* consts = (float*)(ws + WS_CONST);

  const int prep_tasks  = PTOT + NOUT + 64;
  const int prep_blocks = (prep_tasks + 255) / 256;
  prep_kernel<<<prep_blocks, 256, 0, stream>>>(
      sw1, sb1, sw2, sb2, cw1, cb1, cw2, cb2, mw1, mb1, mw2, mb2, pw, edge,
      wh, b1cat, w2cat, consts);

  decoder_main<<<E_EDGES / 32, 256, 0, stream>>>(
      z, chem, edge, mask, wh, b1cat, w2cat, consts, (float*)d_out);
}

// Round 6
// 724.254 us; speedup vs baseline: 1.7560x; 1.7560x over previous
//
#include <hip/hip_runtime.h>

// ---------------------------------------------------------------------------
// ChemistryAwareDecoder on MI355X (gfx950)
// N=100000 nodes, E=200000 edges, SD=128, CD=768
// R6: R1's cooperative coalesced staging (8 consecutive lanes per 128B row
// segment -> 2 cache lines/stream, no cross-wave duplication) fused with
// R5's low-register f16x2 4-wave tile split (40 acc regs/wave, no spill),
// plus 2-step-deep gather prefetch. R5's register-direct gathers scattered
// 16 rows per instruction (~32 lines) x4 duplicated waves -> vector-memory
// line-processing serialized the kernel at 980us with all pipes <12%.
// ---------------------------------------------------------------------------

typedef float    f32x4 __attribute__((ext_vector_type(4)));
typedef _Float16 f16x8 __attribute__((ext_vector_type(8)));
typedef _Float16 f16x4 __attribute__((ext_vector_type(4)));

#define E_EDGES 200000
#define KSTEPS  28                    // 896 / 32
#define NOUT    384                   // 64 + 192 + 128 fused outputs
#define PTOT    (KSTEPS * NOUT * 32)  // 344064 weight elements
#define PANEL   (NOUT * 32)           // 12288 halfs per k-step panel

// workspace layout (bytes)
#define WS_WH    0
#define WS_B1    688128
#define WS_W2    (688128 + 1536)
#define WS_CONST (688128 + 3072)

// ---------------------------------------------------------------------------
// Prep: fused block-diagonal weight panels in f16 (RNE), fused bias/layer-2
// vectors, softmax consts, edge-dtype detection.
// Panel: wh[p][n][kk], p = k/32, n = 0..383, kk = k%32.
// Wbig[k][n]: n<64: sw1 (k<128) | n<256: cw1 (k>=128) | n>=256: mw1 (all k)
// ---------------------------------------------------------------------------
__global__ __launch_bounds__(256) void prep_kernel(
    const float* __restrict__ sw1, const float* __restrict__ sb1,
    const float* __restrict__ sw2, const float* __restrict__ sb2,
    const float* __restrict__ cw1, const float* __restrict__ cb1,
    const float* __restrict__ cw2, const float* __restrict__ cb2,
    const float* __restrict__ mw1, const float* __restrict__ mb1,
    const float* __restrict__ mw2, const float* __restrict__ mb2,
    const float* __restrict__ pw,  const int* __restrict__ edge_i32,
    _Float16* __restrict__ wh,
    float* __restrict__ b1cat, float* __restrict__ w2cat,
    float* __restrict__ consts)
{
  const int idx = blockIdx.x * 256 + threadIdx.x;
  if (idx < PTOT) {
    const int p  = idx / PANEL;
    const int r  = idx % PANEL;
    const int n  = r >> 5;
    const int kk = r & 31;
    const int k  = p * 32 + kk;
    float v;
    if (n < 64)       v = (k < 128)  ? sw1[k * 64 + n] : 0.0f;
    else if (n < 256) v = (k >= 128) ? cw1[(size_t)(k - 128) * 192 + (n - 64)] : 0.0f;
    else              v = mw1[(size_t)k * 128 + (n - 256)];
    wh[idx] = (_Float16)v;  // RNE
  } else if (idx < PTOT + NOUT) {
    const int j = idx - PTOT;
    float b, w;
    if (j < 64)       { b = sb1[j];       w = sw2[j]; }
    else if (j < 256) { b = cb1[j - 64];  w = cw2[j - 64]; }
    else              { b = mb1[j - 256]; w = mw2[j - 256]; }
    b1cat[j] = b;
    w2cat[j] = w;
  } else if (idx == PTOT + NOUT) {
    const float p0 = pw[0], p1 = pw[1], p2 = pw[2];
    const float mx = fmaxf(p0, fmaxf(p1, p2));
    const float e0 = __expf(p0 - mx), e1 = __expf(p1 - mx), e2 = __expf(p2 - mx);
    const float inv = 1.0f / (e0 + e1 + e2);
    const float w0 = e0 * inv, w1 = e1 * inv, w2v = e2 * inv;
    consts[0] = w0; consts[1] = w1; consts[2] = w2v;
    consts[3] = w0 * sb2[0] + w1 * cb2[0] + w2v * mb2[0];  // valid-path bias
    consts[4] = sb2[0];                                    // invalid-path bias
    unsigned o = 0;
    for (int i = 0; i < 64; ++i) o |= (unsigned)edge_i32[2 * i + 1];
    consts[5] = (o == 0u) ? 1.0f : 0.0f;  // 1 => int64 edge layout
  }
}

// f16x2 compensated: (ah+al)*bh = a*bh; error ~ 2^-12 |ab| per term
#define FMA2(ACC, AH, AL, B)                                              \
  ACC = __builtin_amdgcn_mfma_f32_16x16x32_f16(AH, B, ACC, 0, 0, 0);      \
  ACC = __builtin_amdgcn_mfma_f32_16x16x32_f16(AL, B, ACC, 0, 0, 0);

// ---------------------------------------------------------------------------
// Main: grid = E/32 = 6250 blocks of 256 threads (4 waves). Block owns edges
// [32b, 32b+32): M-tile0 rows 0-15, tile1 rows 16-31. N-tiles: 0-3
// structural (k<128), 4-15 chemical (k>=128), 16-23 combined (all k).
// Wave wv owns: S{wv} (phase A), H{4+3wv..6+3wv} (phase B), C{16+2wv,17+2wv}
// (both). Staging is block-cooperative & coalesced: thread tid loads 16B of
// edge (tid>>3)'s src and dst rows at k-chunk (tid&7)*4; products split f16
// hi/lo into double-buffered LDS. 2-step gather prefetch. 1 barrier/step.
// ---------------------------------------------------------------------------
__global__ __launch_bounds__(256, 3) void decoder_main(
    const float* __restrict__ z, const float* __restrict__ chem,
    const int* __restrict__ edge, const int* __restrict__ mask,
    const _Float16* __restrict__ wh,
    const float* __restrict__ b1cat, const float* __restrict__ w2cat,
    const float* __restrict__ consts, float* __restrict__ out)
{
  __shared__ _Float16 Ah[2][32][40];  // stride 40 halfs: 16B-aligned, 2-way banks
  __shared__ _Float16 Al[2][32][40];
  __shared__ int   srcL[32];
  __shared__ int   dstL[32];
  __shared__ float validL[32];
  __shared__ float scoreW[4][32];

  const int tid  = threadIdx.x;
  const int lane = tid & 63;
  const int wv   = tid >> 6;
  const int li   = lane & 15;
  const int q    = lane >> 4;
  const int base = blockIdx.x * 32;   // E = 6250*32 exactly

  if (tid < 32) {
    const int e = base + tid;
    int s_, d_;
    if (consts[5] > 0.5f) { s_ = edge[4 * e]; d_ = edge[4 * e + 2]; }  // int64
    else                  { s_ = edge[2 * e]; d_ = edge[2 * e + 1]; }  // int32
    srcL[tid] = s_;
    dstL[tid] = d_;
    validL[tid] = (mask[s_] != 0 && mask[d_] != 0) ? 1.0f : 0.0f;
  }
  __syncthreads();

  // cooperative staging slots: edge row m, k-chunk kc (coalesced: 8
  // consecutive lanes cover one 128B row segment)
  const int m  = tid >> 3;
  const int kc = (tid & 7) << 2;
  const float* zs = z    + (size_t)srcL[m] * 128 + kc;
  const float* zd = z    + (size_t)dstL[m] * 128 + kc;
  const float* cs = chem + (size_t)srcL[m] * 768 + kc;
  const float* cd = chem + (size_t)dstL[m] * 768 + kc;

  // gather for k-step t (t<4: z, else chem)
#define GLOAD(T, A, B)                                      \
  if ((T) < 4) {                                            \
    A = *(const f32x4*)(zs + (T) * 32);                     \
    B = *(const f32x4*)(zd + (T) * 32);                     \
  } else {                                                  \
    A = *(const f32x4*)(cs + ((T) - 4) * 32);               \
    B = *(const f32x4*)(cd + ((T) - 4) * 32);               \
  }

  // product -> f16 hi/lo -> LDS (4 values, 8B to Ah + 8B to Al)
#define STAGE(BUF, PA, PB)                                  \
  {                                                         \
    f16x4 h_, l_;                                           \
    _Pragma("unroll")                                       \
    for (int j = 0; j < 4; ++j) {                           \
      const float p_ = (PA)[j] * (PB)[j];                   \
      const _Float16 hh = (_Float16)p_;                     \
      h_[j] = hh;                                           \
      l_[j] = (_Float16)(p_ - (float)hh);                   \
    }                                                       \
    *(f16x4*)&Ah[BUF][m][kc] = h_;                          \
    *(f16x4*)&Al[BUF][m][kc] = l_;                          \
  }

  // B fragment: tile ti at step s (proven panel indexing)
#define BFRAG(S, TI) \
  (*(const f16x8*)(wh + (size_t)(S) * PANEL + ((TI) * 16 + li) * 32 + q * 8))

  // A fragments for this wave (2 M-tiles) from LDS buffer
#define AFRAGS(BUF, A0H, A0L, A1H, A1L)                     \
  A0H = *(const f16x8*)&Ah[BUF][li][q * 8];                 \
  A0L = *(const f16x8*)&Al[BUF][li][q * 8];                 \
  A1H = *(const f16x8*)&Ah[BUF][16 + li][q * 8];            \
  A1L = *(const f16x8*)&Al[BUF][16 + li][q * 8];

  const float w0c = consts[0], w1c = consts[1], w2c = consts[2];

  float part[2][4];
#pragma unroll
  for (int mt = 0; mt < 2; ++mt)
#pragma unroll
    for (int r = 0; r < 4; ++r) part[mt][r] = 0.0f;

  // retire one tile's acc into part with path weighting.
  // C/D layout: col = ti*16+li, row = q*4+r (+16 for tile1).
#define RETIRE(ACC, TI, MT, WVALID, WINVALID)                              \
  {                                                                        \
    const int col = (TI) * 16 + li;                                        \
    const float b1 = b1cat[col];                                           \
    const float w2 = w2cat[col];                                           \
    _Pragma("unroll")                                                      \
    for (int r = 0; r < 4; ++r) {                                          \
      const float vld = validL[(MT) * 16 + q * 4 + r];                     \
      const float a = (WINVALID) + vld * ((WVALID) - (WINVALID));          \
      part[MT][r] += a * fmaxf((ACC)[r] + b1, 0.0f) * w2;                  \
    }                                                                      \
  }

  // this wave's tile indices
  const int tS  = wv;             // structural, phase A
  const int tH0 = 4 + 3 * wv;     // chemical, phase B
  const int tC0 = 16 + 2 * wv;    // combined, both phases

  // ---- pipeline prologue: stage s=0; prefetch s=1 --------------------
  {
    f32x4 a0, b0;
    GLOAD(0, a0, b0)
    STAGE(0, a0, b0)
  }
  f32x4 gca, gcb;   // gathers for step s+1 (consumed next STAGE)
  GLOAD(1, gca, gcb)
  __syncthreads();

  // ---------------- phase A: s = 0..3 (S + C tiles) ----------------------
  f32x4 accS[2], accC[2][2];
  accS[0] = (f32x4){0.f, 0.f, 0.f, 0.f};
  accS[1] = (f32x4){0.f, 0.f, 0.f, 0.f};
#pragma unroll
  for (int t = 0; t < 2; ++t) {
    accC[t][0] = (f32x4){0.f, 0.f, 0.f, 0.f};
    accC[t][1] = (f32x4){0.f, 0.f, 0.f, 0.f};
  }

#pragma unroll
  for (int s = 0; s < 4; ++s) {
    const int buf = s & 1;
    f16x8 a0h, a0l, a1h, a1l;
    AFRAGS(buf, a0h, a0l, a1h, a1l)

    const f16x8 bS  = BFRAG(s, tS);
    const f16x8 bC0 = BFRAG(s, tC0);
    const f16x8 bC1 = BFRAG(s, tC0 + 1);

    // prefetch s+2 (two full steps to land)
    f32x4 gna, gnb;
    GLOAD(s + 2, gna, gnb)

    FMA2(accS[0], a0h, a0l, bS)
    FMA2(accS[1], a1h, a1l, bS)
    FMA2(accC[0][0], a0h, a0l, bC0)
    FMA2(accC[0][1], a1h, a1l, bC0)
    FMA2(accC[1][0], a0h, a0l, bC1)
    FMA2(accC[1][1], a1h, a1l, bC1)

    STAGE(buf ^ 1, gca, gcb)   // stage s+1 from the older prefetch
    __syncthreads();
    gca = gna; gcb = gnb;
  }

  // retire structural (k-range done): valid ? w0 : 1
  RETIRE(accS[0], tS, 0, w0c, 1.0f)
  RETIRE(accS[1], tS, 1, w0c, 1.0f)

  // ---------------- phase B: s = 4..27 (H + C tiles) ----------------------
  f32x4 accH[3][2];
#pragma unroll
  for (int t = 0; t < 3; ++t) {
    accH[t][0] = (f32x4){0.f, 0.f, 0.f, 0.f};
    accH[t][1] = (f32x4){0.f, 0.f, 0.f, 0.f};
  }

  for (int s = 4; s < KSTEPS; ++s) {
    const int buf = s & 1;
    f16x8 a0h, a0l, a1h, a1l;
    AFRAGS(buf, a0h, a0l, a1h, a1l)

    const f16x8 bH0 = BFRAG(s, tH0);
    const f16x8 bH1 = BFRAG(s, tH0 + 1);
    const f16x8 bH2 = BFRAG(s, tH0 + 2);
    const f16x8 bC0 = BFRAG(s, tC0);
    const f16x8 bC1 = BFRAG(s, tC0 + 1);

    f32x4 gna, gnb;
    const bool pf = (s + 2 < KSTEPS);
    if (pf) {
      gna = *(const f32x4*)(cs + (s - 2) * 32);   // (s+2)-4
      gnb = *(const f32x4*)(cd + (s - 2) * 32);
    }

    FMA2(accH[0][0], a0h, a0l, bH0)
    FMA2(accH[0][1], a1h, a1l, bH0)
    FMA2(accH[1][0], a0h, a0l, bH1)
    FMA2(accH[1][1], a1h, a1l, bH1)
    FMA2(accH[2][0], a0h, a0l, bH2)
    FMA2(accH[2][1], a1h, a1l, bH2)
    FMA2(accC[0][0], a0h, a0l, bC0)
    FMA2(accC[0][1], a1h, a1l, bC0)
    FMA2(accC[1][0], a0h, a0l, bC1)
    FMA2(accC[1][1], a1h, a1l, bC1)

    if (s + 1 < KSTEPS) STAGE(buf ^ 1, gca, gcb)
    __syncthreads();
    if (pf) { gca = gna; gcb = gnb; }
  }

  // retire chemical (valid ? w1 : 0) and combined (valid ? w2 : 0)
#pragma unroll
  for (int t = 0; t < 3; ++t) {
    RETIRE(accH[t][0], tH0 + t, 0, w1c, 0.0f)
    RETIRE(accH[t][1], tH0 + t, 1, w1c, 0.0f)
  }
#pragma unroll
  for (int t = 0; t < 2; ++t) {
    RETIRE(accC[t][0], tC0 + t, 0, w2c, 0.0f)
    RETIRE(accC[t][1], tC0 + t, 1, w2c, 0.0f)
  }

  // ---------------- reduce 16 cols per quad (uniform flow) ---------------
#pragma unroll
  for (int mt = 0; mt < 2; ++mt) {
#pragma unroll
    for (int r = 0; r < 4; ++r) {
      float vv = part[mt][r];
      vv += __shfl_xor(vv, 1);
      vv += __shfl_xor(vv, 2);
      vv += __shfl_xor(vv, 4);
      vv += __shfl_xor(vv, 8);
      part[mt][r] = vv;   // full sum now in every lane
    }
  }
  // per-wave partials to LDS (plain stores; no cross-lane in divergent flow)
  if (li == 0) {
#pragma unroll
    for (int mt = 0; mt < 2; ++mt)
#pragma unroll
      for (int r = 0; r < 4; ++r)
        scoreW[wv][mt * 16 + q * 4 + r] = part[mt][r];
  }
  __syncthreads();

  // final cross-wave sum + bias select
  if (tid < 32) {
    const float s4 = scoreW[0][tid] + scoreW[1][tid] + scoreW[2][tid] + scoreW[3][tid];
    const float c3 = consts[3], c4 = consts[4];
    out[base + tid] = s4 + c4 + validL[tid] * (c3 - c4);
  }
}

// ---------------------------------------------------------------------------
extern "C" void kernel_launch(void* const* d_in, const int* in_sizes, int n_in,
                              void* d_out, int out_size, void* d_ws, size_t ws_size,
                              hipStream_t stream)
{
  const float* z    = (const float*)d_in[0];
  const float* chem = (const float*)d_in[1];
  const int*   edge = (const int*)d_in[2];
  const int*   mask = (const int*)d_in[3];
  const float* sw1  = (const float*)d_in[4];
  const float* sb1  = (const float*)d_in[5];
  const float* sw2  = (const float*)d_in[6];
  const float* sb2  = (const float*)d_in[7];
  const float* cw1  = (const float*)d_in[8];
  const float* cb1  = (const float*)d_in[9];
  const float* cw2  = (const float*)d_in[10];
  const float* cb2  = (const float*)d_in[11];
  const float* mw1  = (const float*)d_in[12];
  const float* mb1  = (const float*)d_in[13];
  const float* mw2  = (const float*)d_in[14];
  const float* mb2  = (const float*)d_in[15];
  const float* pw   = (const float*)d_in[16];

  char* ws = (char*)d_ws;
  _Float16* wh  = (_Float16*)(ws + WS_WH);
  float* b1cat  = (float*)(ws + WS_B1);
  float* w2cat  = (float*)(ws + WS_W2);
  float* consts = (float*)(ws + WS_CONST);

  const int prep_tasks  = PTOT + NOUT + 64;
  const int prep_blocks = (prep_tasks + 255) / 256;
  prep_kernel<<<prep_blocks, 256, 0, stream>>>(
      sw1, sb1, sw2, sb2, cw1, cb1, cw2, cb2, mw1, mb1, mw2, mb2, pw, edge,
      wh, b1cat, w2cat, consts);

  decoder_main<<<E_EDGES / 32, 256, 0, stream>>>(
      z, chem, edge, mask, wh, b1cat, w2cat, consts, (float*)d_out);
}